// Round 6
// baseline (192.392 us; speedup 1.0000x reference)
//
#include <hip/hip_runtime.h>

// LIF recurrence: u_t = decay*u_{t-1} + x_t - o_{t-1}*VTH ; o_t = (u_t - VTH > 0)
// x: [B=64, N=4096, T=100] f32, T contiguous (400 B per neuron row).
//
// R12 = R11 (row-aligned 6.4 KB chunk window, 16 waves/CU) + phase barriers.
//
// Why R7/R11 failed (same absmax = max|x|: raw input reached the output):
// the store phase re-reads LDS addresses the SAME thread wrote during
// staging; the intervening compute writes are CROSS-LANE only. Per-thread
// memory semantics allow the compiler to store-to-load-forward the staged
// register straight to the global store, bypassing other lanes' compute
// writes. No-barrier cross-lane LDS handoff is illegal to rely on.
// Fix: __syncthreads() at each phase boundary (cheap for a single-wave
// block; semantically it forbids the forwarding). R6 only survives because
// its alias pattern happens to be opaque to the optimizer.
//
// Experiment this round (the cell never measured): clean R6-shaped traffic
// AT high occupancy. Five clean kernels pin at write-BW ~1.6 TB/s at <=12%
// occupancy; R8 (32% occ, dirty traffic) hit 3.05 TB/s raw. Chunking makes
// LDS 25.6 KB -> 6.4 KB => grid-limited 16 blocks/CU (4 waves/SIMD).
//   - chunk = 16 whole rows (400 f4); 4 chunks/slab; no cross-chunk carry.
//   - stage: 6 wave-wide 1 KB loads + one 16-lane 256 B load (full lines).
//   - compute: lanes 16c..16c+15 run their ENTIRE 100-step row (verbatim
//     bit-exact R6 expression; decay=0.5, o*VTH in {0,0.5} exact).
//   - store: same coalesced full-line shape, cached (R10: policy is a
//     non-factor).

#define VTH 0.5f
#define T_STEPS 100
#define W 64                   // neurons per block == threads per block (1 wave)
#define K 25                   // float4s per neuron row (100 floats)
#define RPC 16                 // rows per chunk
#define NCHUNK 4               // W / RPC
#define CHUNK_F4 (RPC * K)     // 400 float4s = 6,400 B window

typedef float vfloat4 __attribute__((ext_vector_type(4)));

__global__ __launch_bounds__(64, 4) void lif_kernel(const float* __restrict__ x,
                                                    const float* __restrict__ decay_p,
                                                    float* __restrict__ out,
                                                    int n_neurons) {
    __shared__ vfloat4 w4[CHUNK_F4];   // 6,400 B window

    const int lane = threadIdx.x;
    const float decay = decay_p[0];
    const size_t base_f4 = (size_t)blockIdx.x * (W * K);

    const vfloat4* __restrict__ g4 = (const vfloat4*)x + base_f4;
    vfloat4* __restrict__ o4 = (vfloat4*)out + base_f4;

    for (int c = 0; c < NCHUNK; ++c) {
        const int cbase = c * CHUNK_F4;

        // ---- Stage chunk c: issue all global loads first (register-landed;
        // safe to overlap the previous chunk's store reads).
        vfloat4 v[6], v6;
        #pragma unroll
        for (int j = 0; j < 6; ++j) v[j] = g4[cbase + j * W + lane];
        if (lane < 16) v6 = g4[cbase + 6 * W + lane];

        // WAR fence: previous chunk's store-phase LDS reads must complete
        // before the window is overwritten.
        __syncthreads();

        #pragma unroll
        for (int j = 0; j < 6; ++j) w4[j * W + lane] = v[j];
        if (lane < 16) w4[6 * W + lane] = v6;

        // RAW fence: staged data visible to the (cross-lane) compute readers.
        __syncthreads();

        // ---- Compute: lanes 16c..16c+15 own rows 16c..16c+15 of the slab;
        // each runs its full 100-step recurrence. In-place x -> o.
        if ((lane >> 4) == c) {
            const int r = lane & 15;
            float u = 0.0f, o = 0.0f;
            #pragma unroll
            for (int i = 0; i < K; ++i) {
                vfloat4 t = w4[r * K + i];
                u = decay * u + t.x - o * VTH; o = (u > VTH) ? 1.0f : 0.0f; t.x = o;
                u = decay * u + t.y - o * VTH; o = (u > VTH) ? 1.0f : 0.0f; t.y = o;
                u = decay * u + t.z - o * VTH; o = (u > VTH) ? 1.0f : 0.0f; t.z = o;
                u = decay * u + t.w - o * VTH; o = (u > VTH) ? 1.0f : 0.0f; t.w = o;
                w4[r * K + i] = t;
            }
        }

        // RAW fence: compute writes visible to the (cross-lane) store reads.
        // This is the barrier whose absence let the compiler forward staged
        // input registers straight to the output stores in R7/R11.
        __syncthreads();

        // ---- Store chunk c: same coalesced full-line shape (cached).
        #pragma unroll
        for (int j = 0; j < 6; ++j) o4[cbase + j * W + lane] = w4[j * W + lane];
        if (lane < 16) o4[cbase + 6 * W + lane] = w4[6 * W + lane];
    }
}

extern "C" void kernel_launch(void* const* d_in, const int* in_sizes, int n_in,
                              void* d_out, int out_size, void* d_ws, size_t ws_size,
                              hipStream_t stream) {
    const float* x = (const float*)d_in[0];
    const float* decay = (const float*)d_in[1];
    float* out = (float*)d_out;

    const int n_neurons = in_sizes[0] / T_STEPS;   // 262,144
    const int grid = n_neurons / W;                // 4096 single-wave blocks

    lif_kernel<<<grid, W, 0, stream>>>(x, decay, out, n_neurons);
}

// Round 7
// 190.271 us; speedup vs baseline: 1.0111x; 1.0111x over previous
//
#include <hip/hip_runtime.h>

// LIF recurrence: u_t = decay*u_{t-1} + x_t - o_{t-1}*VTH ; o_t = (u_t - VTH > 0)
// x: [B=64, N=4096, T=100] f32, T contiguous (400 B per neuron row).
//
// R13: write-stream address decorrelation. Ledger so far (per-dispatch):
//   R6  burst, NT stores:        63.5 us, write-side 1.61 TB/s
//   R8  no-LDS scatter:          138 us,  write-side 1.57 TB/s (2x traffic)
//   R9  producer/consumer:       64 us,   write-side 1.58 TB/s
//   R10 cached stores:           63.5 us, write-side 1.61 TB/s
//   R12 6.4KB chunks, 30% occ:   68 us,   write-side 1.51 TB/s
// Write BW pinned ~1.6 TB/s (half of copy-class ~3.15) across policy,
// occupancy, schedule, pattern. Untested axis: address<->time correlation.
// All variants map block b -> slab b (contiguous 100 KB) and store k=0..24
// in order. Channel arithmetic: slab stride 102400 B == 4096 mod 8192, so
// concurrent lockstep blocks storing the same k concentrate on ~8/32
// channels at any instant. Fix, traffic-shape preserved exactly:
//   1. bit-reversed block->slab mapping (bijection on 4096 slabs)
//   2. per-block rotated store/load order: start = 7*blockIdx mod 25
//   3. phase barriers (kills the R7/R11 LDS store-to-load-forward hazard)
// Compute expression verbatim from bit-exact R6 (decay=0.5, o*VTH exact).

#define VTH 0.5f
#define T_STEPS 100
#define W 64                  // neurons per block == threads per block (1 wave)
#define K 25                  // float4s per neuron row (100 floats)

typedef float vfloat4 __attribute__((ext_vector_type(4)));

__global__ __launch_bounds__(64) void lif_kernel(const float* __restrict__ x,
                                                 const float* __restrict__ decay_p,
                                                 float* __restrict__ out,
                                                 int n_neurons) {
    __shared__ vfloat4 lds4[W * K];   // 25,600 B flat mirror of this block's slab

    const int lane = threadIdx.x;
    const float decay = decay_p[0];

    // Bit-reversed block->slab mapping: 4096 = 2^12 slabs; __brev reverses
    // 32 bits, shift keeps the low-12 reversal. Bijection; concurrent blocks
    // (adjacent IDs) land 200 MB apart -> XCD/L3/channel decorrelation.
    const unsigned slab = __brev((unsigned)blockIdx.x) >> 20;
    const size_t base_f4 = (size_t)slab * (W * K);

    const vfloat4* __restrict__ g4 = (const vfloat4*)x + base_f4;
    vfloat4* __restrict__ o4 = (vfloat4*)out + base_f4;

    // Per-block phase rotation of the k-sequence (7 coprime to 25): at any
    // instant, concurrent blocks' stores cover all 25 k-offsets -> all
    // channels, instead of lockstep-concentrating on one k.
    const int start = (int)((7u * blockIdx.x) % 25u);

    // ---- Stage: 25 coalesced 1 KB wave-wide loads (rotated order), all
    // issued before any LDS write, then ds_write_b128 into the slab mirror.
    vfloat4 v[K];
    int kk = start;
    #pragma unroll
    for (int k = 0; k < K; ++k) {
        v[k] = g4[kk * W + lane];
        kk = (kk + 1 < K) ? kk + 1 : 0;
    }
    kk = start;
    #pragma unroll
    for (int k = 0; k < K; ++k) {
        lds4[kk * W + lane] = v[k];
        kk = (kk + 1 < K) ? kk + 1 : 0;
    }

    // RAW fence: staged data -> cross-lane compute readers.
    __syncthreads();

    // ---- Compute: lane owns neuron `lane`; row = float4s [lane*K, lane*K+K).
    // In-place overwrite x -> o. Verbatim bit-exact R6 expression.
    float u = 0.0f, o = 0.0f;
    #pragma unroll
    for (int i = 0; i < K; ++i) {
        vfloat4 t = lds4[lane * K + i];
        u = decay * u + t.x - o * VTH; o = (u > VTH) ? 1.0f : 0.0f; t.x = o;
        u = decay * u + t.y - o * VTH; o = (u > VTH) ? 1.0f : 0.0f; t.y = o;
        u = decay * u + t.z - o * VTH; o = (u > VTH) ? 1.0f : 0.0f; t.z = o;
        u = decay * u + t.w - o * VTH; o = (u > VTH) ? 1.0f : 0.0f; t.w = o;
        lds4[lane * K + i] = t;
    }

    // RAW fence: compute writes -> cross-lane store readers (this barrier's
    // absence is what let the compiler forward staged input straight to the
    // output stores in R7/R11).
    __syncthreads();

    // ---- Store: lane-contiguous LDS reads, line-perfect 1 KB wave-wide
    // stores in rotated order (cached; R10 proved policy is a non-factor).
    kk = start;
    #pragma unroll
    for (int k = 0; k < K; ++k) {
        o4[kk * W + lane] = lds4[kk * W + lane];
        kk = (kk + 1 < K) ? kk + 1 : 0;
    }
}

extern "C" void kernel_launch(void* const* d_in, const int* in_sizes, int n_in,
                              void* d_out, int out_size, void* d_ws, size_t ws_size,
                              hipStream_t stream) {
    const float* x = (const float*)d_in[0];
    const float* decay = (const float*)d_in[1];
    float* out = (float*)d_out;

    const int n_neurons = in_sizes[0] / T_STEPS;   // 262,144
    const int grid = n_neurons / W;                // 4096 single-wave blocks

    lif_kernel<<<grid, W, 0, stream>>>(x, decay, out, n_neurons);
}

// Round 8
// 185.935 us; speedup vs baseline: 1.0347x; 1.0233x over previous
//
#include <hip/hip_runtime.h>

// LIF recurrence: u_t = decay*u_{t-1} + x_t - o_{t-1}*VTH ; o_t = (u_t - VTH > 0)
// x: [B=64, N=4096, T=100] f32, T contiguous (400 B per neuron row).
//
// R14: store-path cache-scope bypass. Clean-schedule ledger: R6 63.5us,
// R9 64, R10 63.5, R12 68 (30% occ), R13 66.5 (bit-reversed + rotated) --
// policy/occupancy/schedule/address axes all null. Physical-traffic model:
// reads 105 MB (51 HBM + 54 L3) + write-allocate 105 + L3 evict 102 +
// evicted-input refetch 51 = ~363 MB / 63.5us = 5.7 TB/s -- the fabric is
// ALREADY at copy-class rates; the waste is the L3 write-allocate round
// trip (output crosses the fabric twice and evicts exactly half the input,
// FETCH = 51 MB = input/2 every dispatch, stable across all rounds).
// __builtin_nontemporal_store (R10) sets only `nt` and didn't change
// allocation. This round: inline-asm global_store_dwordx4 with `sc0 sc1 nt`
// (system-scope, no L2/L3 allocate, non-temporal) on the output stream.
// Structure otherwise byte-for-byte R10 + the two phase barriers (R7/R11
// store-to-load-forwarding hazard insurance).
//
// Prediction: FETCH 51 -> <20 MB (input stays L3-resident), dur 63.5 ->
// 42-52 us. If null: declare roofline (fabric-saturated at ~5.7 TB/s).
//
// Compute expression verbatim from bit-exact R6 (decay=0.5 and o*VTH in
// {0,0.5} are exact products; absmax 0.0 in every passing round).

#define VTH 0.5f
#define T_STEPS 100
#define W 64                  // neurons per block == threads per block (1 wave)
#define K 25                  // float4s per neuron row (100 floats)

typedef float vfloat4 __attribute__((ext_vector_type(4)));

__global__ __launch_bounds__(64) void lif_kernel(const float* __restrict__ x,
                                                 const float* __restrict__ decay_p,
                                                 float* __restrict__ out,
                                                 int n_neurons) {
    __shared__ vfloat4 lds4[W * K];   // 25,600 B flat mirror of this block's slab

    const int lane = threadIdx.x;
    const float decay = decay_p[0];
    const size_t base_f4 = (size_t)blockIdx.x * (W * K);

    const vfloat4* __restrict__ g4 = (const vfloat4*)x + base_f4;
    vfloat4* __restrict__ o4 = (vfloat4*)out + base_f4;

    // ---- Stage: 25 coalesced 1 KB wave-wide loads, all issued before any
    // LDS write, then ds_write_b128 into the flat slab layout.
    vfloat4 v[K];
    #pragma unroll
    for (int k = 0; k < K; ++k) v[k] = g4[k * W + lane];
    #pragma unroll
    for (int k = 0; k < K; ++k) lds4[k * W + lane] = v[k];

    // RAW fence: staged data -> cross-lane compute readers.
    __syncthreads();

    // ---- Compute: lane owns neuron `lane`; row = float4s [lane*K, lane*K+K).
    // In-place overwrite x -> o.
    float u = 0.0f, o = 0.0f;
    #pragma unroll
    for (int i = 0; i < K; ++i) {
        vfloat4 t = lds4[lane * K + i];
        u = decay * u + t.x - o * VTH; o = (u > VTH) ? 1.0f : 0.0f; t.x = o;
        u = decay * u + t.y - o * VTH; o = (u > VTH) ? 1.0f : 0.0f; t.y = o;
        u = decay * u + t.z - o * VTH; o = (u > VTH) ? 1.0f : 0.0f; t.z = o;
        u = decay * u + t.w - o * VTH; o = (u > VTH) ? 1.0f : 0.0f; t.w = o;
        lds4[lane * K + i] = t;
    }

    // RAW fence: compute writes -> cross-lane store readers (absence of this
    // barrier is what sank R7/R11 via store-to-load forwarding).
    __syncthreads();

    // ---- Store: lane-contiguous LDS reads, line-perfect 1 KB wave-wide
    // stores with explicit cache-scope bypass: sc0 sc1 nt = system-scope,
    // non-allocating, non-temporal. (The A/B variable vs R10's plain store.)
    #pragma unroll
    for (int k = 0; k < K; ++k) {
        vfloat4 d = lds4[k * W + lane];
        vfloat4* p = &o4[k * W + lane];
        asm volatile("global_store_dwordx4 %0, %1, off sc0 sc1 nt"
                     :: "v"(p), "v"(d) : "memory");
    }
}

extern "C" void kernel_launch(void* const* d_in, const int* in_sizes, int n_in,
                              void* d_out, int out_size, void* d_ws, size_t ws_size,
                              hipStream_t stream) {
    const float* x = (const float*)d_in[0];
    const float* decay = (const float*)d_in[1];
    float* out = (float*)d_out;

    const int n_neurons = in_sizes[0] / T_STEPS;   // 262,144
    const int grid = n_neurons / W;                // 4096 single-wave blocks

    lif_kernel<<<grid, W, 0, stream>>>(x, decay, out, n_neurons);
}